// Round 4
// baseline (1206.323 us; speedup 1.0000x reference)
//
#include <hip/hip_runtime.h>
#include <math.h>

#define T_LEN 512
#define H_DIM 50

// Force the multiply operands into ARCH VGPRs. Rounds 1-3 showed the
// allocator homes long-lived per-thread arrays in AGPRs (VGPR_Count=44 with
// a 50-float array!), costing a v_accvgpr_read per use -> 2x VALU inflation.
// The "v" constraint pins the vreg class to VGPR_32.
#define FMAC(acc, w, h) asm("v_fmac_f32 %0, %1, %2" : "+v"(acc) : "v"(w), "v"(h))

__device__ __forceinline__ float sigmoid_f(float v) {
    return 1.0f / (1.0f + __expf(-v));
}
// tanh via fast exp; saturates correctly for large |v| (exp->inf/0).
__device__ __forceinline__ float tanh_f(float v) {
    return 1.0f - 2.0f / (__expf(2.0f * v) + 1.0f);
}

// Block = 256 threads = 4 waves = ONE batch element for the whole T=512
// recurrence. Wave w owns gate w (0=i,1=f,2=g,3=o); lane u owns unit u's row:
// 50 weights per thread, asm-pinned in VGPRs. Every wave keeps a redundant
// replica of (c, h): per step it writes its activated gate to a
// double-buffered LDS exchange, ONE barrier, reads all four gates, updates
// its replica (bitwise-identical across waves), and writes h to its own
// PRIVATE h buffer (within-wave RAW only -> no second barrier, no leader).
__global__ __launch_bounds__(256, 4) void lstm_fused(
    const float* __restrict__ x,
    const float* __restrict__ W_ih,
    const float* __restrict__ W_hh,
    const float* __restrict__ b_ih,
    const float* __restrict__ b_hh,
    const float* __restrict__ W_fc,
    const float* __restrict__ b_fc,
    float* __restrict__ out)
{
    const int b   = blockIdx.x;
    const int tid = threadIdx.x;
    const int w   = tid >> 6;               // gate index 0..3 (0=i,1=f,2=g,3=o)
    const int u   = tid & 63;               // unit lane 0..63
    const bool act = (u < H_DIM);
    const int uc  = act ? u : (H_DIM - 1);  // clamp inactive lanes to unit 49

    __shared__ float xs[T_LEN];             // this batch element's inputs (I=1)
    __shared__ float hs[4][52];             // per-WAVE private h (no dbuf needed)
    __shared__ float gl[2][4][66];          // activated gates, double-buffered

    // Stage x: 512 floats, 256 threads x float2 (coalesced).
    {
        const float2* xb2 = reinterpret_cast<const float2*>(x + (size_t)b * T_LEN);
        reinterpret_cast<float2*>(xs)[tid] = xb2[tid];
    }
    if (u < 52) hs[w][u] = 0.0f;

    // One-time weight load: W_hh row w*50+uc (50 floats; rows 200B apart).
    float W[H_DIM];
    const int row    = w * H_DIM + uc;      // in [0,200)
    const float wih  = W_ih[row];           // W_ih is [200][1]
    const float bias = b_ih[row] + b_hh[row];
    {
        const float2* wr = reinterpret_cast<const float2*>(W_hh + (size_t)row * H_DIM);
        #pragma unroll
        for (int j = 0; j < H_DIM / 2; ++j) {
            const float2 t2 = wr[j];
            W[2 * j]     = t2.x;
            W[2 * j + 1] = t2.y;
        }
    }

    float c = 0.0f, hv = 0.0f;              // replicated state (identical per wave)
    __syncthreads();                        // xs ready

    auto step = [&](int buf, int t) {
        const float xv = xs[t];             // broadcast read

        // a = bias + wih*x_t + W_row . h   (4 independent asm-FMA chains)
        float a0 = bias, a1 = 0.f, a2 = 0.f, a3 = 0.f;
        FMAC(a0, xv, wih);
        const float4* hb = reinterpret_cast<const float4*>(hs[w]);
        #pragma unroll
        for (int q = 0; q < 12; ++q) {
            const float4 h4 = hb[q];        // broadcast ds_read_b128 (own buffer)
            FMAC(a0, W[4 * q + 0], h4.x);
            FMAC(a1, W[4 * q + 1], h4.y);
            FMAC(a2, W[4 * q + 2], h4.z);
            FMAC(a3, W[4 * q + 3], h4.w);
        }
        {
            const float2 h2 = *reinterpret_cast<const float2*>(&hs[w][48]);
            FMAC(a0, W[48], h2.x);
            FMAC(a1, W[49], h2.y);
        }
        const float a = (a0 + a2) + (a1 + a3);

        // Gate activation (branch uniform per wave), publish to exchange.
        const float v = (w == 2) ? tanh_f(a) : sigmoid_f(a);
        gl[buf][w][u] = v;
        __syncthreads();                    // the ONE barrier per step

        // Redundant cell update on every wave (bitwise-identical).
        const float gi = gl[buf][0][u];
        const float gf = gl[buf][1][u];
        const float gg = gl[buf][2][u];
        const float go = gl[buf][3][u];
        c  = __fmaf_rn(gf, c, gi * gg);
        hv = go * tanh_f(c);
        if (act) hs[w][u] = hv;             // own-wave buffer: lgkmcnt orders RAW
    };

    for (int t = 0; t < T_LEN; t += 2) {    // dbuf of gl: waves stay <=1 barrier apart
        step(0, t);
        step(1, t + 1);
    }

    // out[b] = h . W_fc + b_fc  (h is live in registers on every wave; wave 0 reports)
    if (w == 0) {
        float part = act ? hv * W_fc[uc] : 0.0f;
        #pragma unroll
        for (int off = 32; off > 0; off >>= 1) part += __shfl_down(part, off);
        if (u == 0) out[b] = part + b_fc[0];
    }
}

extern "C" void kernel_launch(void* const* d_in, const int* in_sizes, int n_in,
                              void* d_out, int out_size, void* d_ws, size_t ws_size,
                              hipStream_t stream) {
    const float* x    = (const float*)d_in[0];
    const float* W_ih = (const float*)d_in[1];
    const float* W_hh = (const float*)d_in[2];
    const float* b_ih = (const float*)d_in[3];
    const float* b_hh = (const float*)d_in[4];
    const float* W_fc = (const float*)d_in[5];
    const float* b_fc = (const float*)d_in[6];
    float* out = (float*)d_out;

    const int B = in_sizes[0] / T_LEN;   // 4096
    lstm_fused<<<dim3(B), dim3(256), 0, stream>>>(x, W_ih, W_hh, b_ih, b_hh, W_fc, b_fc, out);
}

// Round 6
// 802.956 us; speedup vs baseline: 1.5024x; 1.5024x over previous
//
#include <hip/hip_runtime.h>
#include <math.h>

#define T_LEN 512
#define H_DIM 50
#define LOG2E 1.44269504088896f

typedef _Float16 h2_t __attribute__((ext_vector_type(2)));

// Fallback (also satisfies the HOST compile pass, where the amdgcn builtin
// doesn't exist). Defined BEFORE the kernel — round 5 failed host-compile
// because this was below the use site.
__device__ __forceinline__ float dot2_emul(int wd, int hd, float acc) {
    const h2_t wv = __builtin_bit_cast(h2_t, wd);
    const h2_t hv = __builtin_bit_cast(h2_t, hd);
    acc = __fmaf_rn((float)wv.x, (float)hv.x, acc);
    acc = __fmaf_rn((float)wv.y, (float)hv.y, acc);
    return acc;
}

#if defined(__has_builtin)
#if __has_builtin(__builtin_amdgcn_fdot2)
#define DOT2(wd, hd, accv) __builtin_amdgcn_fdot2(                             \
        __builtin_bit_cast(h2_t, wd), __builtin_bit_cast(h2_t, hd), accv, false)
#endif
#endif
#ifndef DOT2
#define DOT2(wd, hd, accv) dot2_emul(wd, hd, accv)
#endif

template <int CTRL>
__device__ __forceinline__ float dppf(float v) {
    return __int_as_float(__builtin_amdgcn_mov_dpp(__float_as_int(v), CTRL, 0xF, 0xF, true));
}
#define DPP_XOR1 0xB1   // quad_perm [1,0,3,2]
#define DPP_XOR2 0x4E   // quad_perm [2,3,0,1]
#define DPP_SHL4 0x104  // row_shl:4 -> dest lane i reads src lane i+4

// Block = 256 threads = 4 waves = ONE batch element.
// Lane packing: lane = 4*k + pos; quad k of wave w owns hidden unit u=16w+k,
// pos encodes the gate (pos0=i, pos1=g[tanh], pos2=f, pos3=o). Each thread
// holds ONE W_hh row packed as 25 f16x2 dwords and computes its gate via
// v_dot2_f32_f16. All 4 gates of a unit sit in one quad -> cell update is a
// pure-VALU DPP butterfly (no LDS gate exchange, no leader). h is exchanged
// as 25 packed f16x2 dwords in double-buffered LDS (broadcast reads); c is
// f32, replicated per lane. Units 50..63 are dummies (clamped row, no write).
__global__ __launch_bounds__(256, 4) void lstm_fused(
    const float* __restrict__ x,
    const float* __restrict__ W_ih,
    const float* __restrict__ W_hh,
    const float* __restrict__ b_ih,
    const float* __restrict__ b_hh,
    const float* __restrict__ W_fc,
    const float* __restrict__ b_fc,
    float* __restrict__ out)
{
    const int b    = blockIdx.x;
    const int tid  = threadIdx.x;
    const int w    = tid >> 6;
    const int lane = tid & 63;
    const int pos  = lane & 3;
    const int k    = lane >> 2;
    const int unit = w * 16 + k;                       // 0..63; valid < 50
    const int uu   = unit < H_DIM ? unit : H_DIM - 1;
    const int gate = ((pos & 1) << 1) | (pos >> 1);    // pos 0,1,2,3 -> gate 0,2,1,3
    const int row  = gate * H_DIM + uu;                // W row in [0,200)

    __shared__ __align__(16) float xs[T_LEN];
    __shared__ __align__(16) int   hs2[2][32];         // 25 used f16x2 dwords + pad

    // Stage x (I=1): 512 floats via 256x float2.
    {
        const float2* xb2 = reinterpret_cast<const float2*>(x + (size_t)b * T_LEN);
        reinterpret_cast<float2*>(xs)[tid] = xb2[tid];
    }
    if (tid < 64) reinterpret_cast<int*>(hs2)[tid] = 0;

    // Pack this thread's W_hh row into 25 f16x2 dwords (one-time).
    int w2[25];
    const float wih  = W_ih[row];
    const float bias = b_ih[row] + b_hh[row];
    {
        const float2* wr = reinterpret_cast<const float2*>(W_hh + (size_t)row * H_DIM);
        #pragma unroll
        for (int j = 0; j < 25; ++j) {
            const float2 t2 = wr[j];
            w2[j] = __builtin_bit_cast(int, __builtin_amdgcn_cvt_pkrtz(t2.x, t2.y));
        }
    }

    // Per-lane activation constants: sigmoid(a)=1/(1+2^(-a*log2e));
    // tanh(a)=2*sigmoid(2a)-1 -> one exp2/rcp path, no divergence.
    const bool is_g = (pos == 1);
    const float kc = is_g ? (-2.0f * LOG2E) : (-LOG2E);
    const float mc = is_g ? 2.0f : 1.0f;
    const float qc = is_g ? -1.0f : 0.0f;
    const bool o1 = (pos & 1) != 0;
    const bool o2 = (pos & 2) != 0;
    const bool writer = (pos == 0) && ((k & 1) == 0) && (unit < H_DIM);
    const int  widx = 8 * w + (k >> 1);                // h2 dword this quad-pair owns

    float c = 0.0f;
    __syncthreads();

#define STEP(CUR, TT)                                                          \
    {                                                                          \
        const float xv = xs[TT];                                               \
        const int4* hq = reinterpret_cast<const int4*>(hs2[CUR]);              \
        const int4 q0 = hq[0], q1 = hq[1], q2 = hq[2],                         \
                   q3 = hq[3], q4 = hq[4], q5 = hq[5];                         \
        const int s24 = hs2[CUR][24];                                          \
        int hr[25];                                                            \
        hr[0]=q0.x; hr[1]=q0.y; hr[2]=q0.z; hr[3]=q0.w;                        \
        hr[4]=q1.x; hr[5]=q1.y; hr[6]=q1.z; hr[7]=q1.w;                        \
        hr[8]=q2.x; hr[9]=q2.y; hr[10]=q2.z; hr[11]=q2.w;                      \
        hr[12]=q3.x; hr[13]=q3.y; hr[14]=q3.z; hr[15]=q3.w;                    \
        hr[16]=q4.x; hr[17]=q4.y; hr[18]=q4.z; hr[19]=q4.w;                    \
        hr[20]=q5.x; hr[21]=q5.y; hr[22]=q5.z; hr[23]=q5.w;                    \
        hr[24]=s24;                                                            \
        float acc0 = __fmaf_rn(xv, wih, bias), acc1 = 0.0f;                    \
        _Pragma("unroll")                                                      \
        for (int m = 0; m < 24; m += 2) {                                      \
            acc0 = DOT2(w2[m],   hr[m],   acc0);                               \
            acc1 = DOT2(w2[m+1], hr[m+1], acc1);                               \
        }                                                                      \
        acc0 = DOT2(w2[24], hr[24], acc0);                                     \
        const float a = acc0 + acc1;                                           \
        /* activation */                                                       \
        const float ex = __builtin_amdgcn_exp2f(a * kc);                       \
        const float rc = __builtin_amdgcn_rcpf(1.0f + ex);                     \
        const float v  = __fmaf_rn(rc, mc, qc);        /* (I,G,F,O) per quad */\
        /* quad butterfly: all lanes end with c' and h */                      \
        const float t1  = dppf<DPP_XOR1>(v);           /* (G,I,O,F) */         \
        const float u2  = o1 ? t1 : v;                 /* (I,I,F,F) */         \
        const float u3  = o1 ? v : t1;                 /* (G,G,O,O) */         \
        const float sel = o2 ? c : u3;                 /* (G,G,c,c) */         \
        const float pr  = u2 * sel;                    /* (IG,IG,Fc,Fc) */     \
        const float t2  = dppf<DPP_XOR2>(pr);                                  \
        c = pr + t2;                                   /* new cell, all lanes*/\
        const float e2 = __builtin_amdgcn_exp2f(c * (-2.0f * LOG2E));          \
        const float r2 = __builtin_amdgcn_rcpf(1.0f + e2);                     \
        const float tc = __fmaf_rn(r2, 2.0f, -1.0f);   /* tanh(c) */           \
        const float t3 = dppf<DPP_XOR2>(u3);           /* (O,O,G,G) */         \
        const float Ov = o2 ? u3 : t3;                 /* O on all lanes */    \
        const float hv = Ov * tc;                                              \
        /* publish h as f16x2: lane 4k (k even) packs (h_u, h_{u+1}) */        \
        const float hp = dppf<DPP_SHL4>(hv);                                   \
        if (writer)                                                            \
            hs2[(CUR) ^ 1][widx] =                                             \
                __builtin_bit_cast(int, __builtin_amdgcn_cvt_pkrtz(hv, hp));   \
        __syncthreads();                                                       \
    }

    for (int t = 0; t < T_LEN; t += 2) {
        STEP(0, t)
        STEP(1, t + 1)
    }

    // Final h is in hs2[0] as f16x2. out[b] = h . W_fc + b_fc (wave 0).
    if (w == 0) {
        float part = 0.0f;
        if (lane < 25) {
            const h2_t hh = __builtin_bit_cast(h2_t, hs2[0][lane]);
            const float2 wf = reinterpret_cast<const float2*>(W_fc)[lane];
            part = (float)hh.x * wf.x + (float)hh.y * wf.y;
        }
        #pragma unroll
        for (int off = 32; off > 0; off >>= 1) part += __shfl_xor(part, off);
        if (lane == 0) out[b] = part + b_fc[0];
    }
}

extern "C" void kernel_launch(void* const* d_in, const int* in_sizes, int n_in,
                              void* d_out, int out_size, void* d_ws, size_t ws_size,
                              hipStream_t stream) {
    const float* x    = (const float*)d_in[0];
    const float* W_ih = (const float*)d_in[1];
    const float* W_hh = (const float*)d_in[2];
    const float* b_ih = (const float*)d_in[3];
    const float* b_hh = (const float*)d_in[4];
    const float* W_fc = (const float*)d_in[5];
    const float* b_fc = (const float*)d_in[6];
    float* out = (float*)d_out;

    const int B = in_sizes[0] / T_LEN;   // 4096
    lstm_fused<<<dim3(B), dim3(256), 0, stream>>>(x, W_ih, W_hh, b_ih, b_hh, W_fc, b_fc, out);
}

// Round 8
// 207.259 us; speedup vs baseline: 5.8204x; 3.8742x over previous
//
#include <hip/hip_runtime.h>
#include <math.h>

#define T_LEN 512
#define H_DIM 50
#define BPB   16          // batches per block (MFMA N)
#define L2E   1.44269504088896f
#define HSTR  88          // halves per h-row: 44 dwords, %32=12 -> even bank spread
#define XSTR  520         // halves per x-row (512 + pad so [512] stays in-bounds)

typedef _Float16 half8_t __attribute__((ext_vector_type(8)));
typedef float    f32x4_t __attribute__((ext_vector_type(4)));

// Device-guarded: host compile pass may not declare the mfma builtin (round-5 lesson).
__device__ __forceinline__ f32x4_t mfma16(half8_t a, half8_t b, f32x4_t c) {
#if defined(__HIP_DEVICE_COMPILE__)
    return __builtin_amdgcn_mfma_f32_16x16x32_f16(a, b, c, 0, 0, 0);
#else
    return c;
#endif
}

// cvt_pkrtz returns __fp16x2 (NOT _Float16x2) -> bit_cast to int immediately
// (round-7 lesson).
__device__ __forceinline__ int pk16(float a, float b) {
    return __builtin_bit_cast(int, __builtin_amdgcn_cvt_pkrtz(a, b));
}

__device__ __forceinline__ float sigm(float v) {
    return __builtin_amdgcn_rcpf(1.0f + __builtin_amdgcn_exp2f(v * (-L2E)));
}
__device__ __forceinline__ float tanh_f(float v) {
    return __fmaf_rn(
        __builtin_amdgcn_rcpf(1.0f + __builtin_amdgcn_exp2f(v * (-2.0f * L2E))),
        2.0f, -1.0f);
}

// Block = 512 threads = 8 waves = 16 batch elements for the whole recurrence.
// gates[208 x 16] = W'[208 x 64] . H'[64 x 16] via mfma_f32_16x16x32_f16,
// where W' rows are PERMUTED p = 4*unit + gate (so lane L of tile m holds all
// 4 gates of unit 4m+(L>>4), batch L&15 -> lane-local cell update), and
// K dim is augmented: k<50 = W_hh, k=50 = W_ih (H'[50]=x_t), k=51 = bias
// (H'[51]=1), k>=52 zero-pad. 13 real tiles of 16 rows over 8 waves (waves
// 0-4: two tiles; 5-7: one real + one zero-padded fake so all waves run
// identical code). h is exchanged as f16 in double-buffered LDS; one
// ds_read_b128 per K-chunk IS the B-fragment. Weights live in AGPRs where
// MFMA reads them for free (the round-1..6 AGPR-copy curse is void).
__global__ __launch_bounds__(512, 1) void lstm_mfma(
    const float* __restrict__ x,
    const float* __restrict__ W_ih,
    const float* __restrict__ W_hh,
    const float* __restrict__ b_ih,
    const float* __restrict__ b_hh,
    const float* __restrict__ W_fc,
    const float* __restrict__ b_fc,
    float* __restrict__ out)
{
    const int tid = threadIdx.x;
    const int w   = tid >> 6;        // wave 0..7
    const int L   = tid & 63;
    const int col = L & 15;          // batch-in-block == A-row == D-col
    const int g4  = L >> 4;          // lane group 0..3

    __shared__ _Float16 xls[BPB][XSTR];
    __shared__ _Float16 hls[2][BPB][HSTR];

    // ---- stage x (16 batches x 512) f32 -> f16, coalesced float4
    {
        const float4* xg4 = reinterpret_cast<const float4*>(
            x + (size_t)blockIdx.x * BPB * T_LEN);
        #pragma unroll
        for (int r = 0; r < 4; ++r) {
            const int f = tid + 512 * r;         // float4 idx < 2048
            const float4 v = xg4[f];
            const int bb = f >> 7;
            const int c0 = (f & 127) << 2;
            *reinterpret_cast<int*>(&xls[bb][c0])     = pk16(v.x, v.y);
            *reinterpret_cast<int*>(&xls[bb][c0 + 2]) = pk16(v.z, v.w);
        }
    }
    // ---- zero both h buffers (2*16*88 halves = 1408 dwords)
    {
        int* hz = reinterpret_cast<int*>(hls);
        for (int i = tid; i < 2 * BPB * HSTR / 2; i += 512) hz[i] = 0;
    }
    __syncthreads();
    if (tid < BPB) {                 // H'_0 = [h0=0, x_0, 1]
        hls[0][tid][50] = xls[tid][0];
        hls[0][tid][51] = (_Float16)1.0f;
        hls[1][tid][51] = (_Float16)1.0f;
    }

    // ---- per-wave tile assignment (13 real tiles; m>=13 -> zero fake)
    const int m0 = (w < 5) ? 2 * w     : (w + 5);   // 0,2,4,6,8 / 10,11,12
    const int m1 = (w < 5) ? 2 * w + 1 : (w + 8);   // 1,3,5,7,9 / 13,14,15 (fake)

    // ---- one-time A-fragment load: W'[perm p = 16m+col][k = 32kc+8*g4+j]
    auto load_frag = [&](int m, int kc) -> half8_t {
        const int p = 16 * m + col;
        const int u = p >> 2, gg = p & 3;
        half8_t h8;
        #pragma unroll
        for (int j = 0; j < 8; ++j) {
            const int k = 32 * kc + 8 * g4 + j;
            float v = 0.0f;
            if (u < H_DIM) {
                const int r = gg * H_DIM + u;    // torch row: gate*50 + unit
                if (k < H_DIM)     v = W_hh[r * H_DIM + k];
                else if (k == 50)  v = W_ih[r];
                else if (k == 51)  v = b_ih[r] + b_hh[r];
            }
            h8[j] = (_Float16)v;
        }
        return h8;
    };
    const half8_t a00 = load_frag(m0, 0), a01 = load_frag(m0, 1);
    const half8_t a10 = load_frag(m1, 0), a11 = load_frag(m1, 1);

    const int u0  = 4 * m0 + g4;     // unit this lane owns, tile 0/1
    const int u1  = 4 * m1 + g4;
    const bool wr0 = (u0 < H_DIM);
    const bool wr1 = (u1 < H_DIM);
    const bool xw  = (w == 7) && (L < BPB);   // x_{t+1} writer (b = L)

    float c0 = 0.0f, c1 = 0.0f;
    const f32x4_t zero4 = {0.0f, 0.0f, 0.0f, 0.0f};
    __syncthreads();

    #pragma unroll 2
    for (int t = 0; t < T_LEN; ++t) {
        const int cur = t & 1, nxt = cur ^ 1;
        // B-fragments: units 8*g4..+7 per K-chunk, batch=col (one b128 each)
        const half8_t b0 = *reinterpret_cast<const half8_t*>(&hls[cur][col][8 * g4]);
        const half8_t b1 = *reinterpret_cast<const half8_t*>(&hls[cur][col][32 + 8 * g4]);

        f32x4_t acc0 = mfma16(a00, b0, zero4);
        f32x4_t acc1 = mfma16(a10, b0, zero4);
        acc0 = mfma16(a01, b1, acc0);
        acc1 = mfma16(a11, b1, acc1);

        // acc regs = gates (i,f,g,o) of unit u*, batch col — lane-local update
        {
            const float ig = sigm(acc0[0]);
            const float fg = sigm(acc0[1]);
            const float gt = tanh_f(acc0[2]);
            const float og = sigm(acc0[3]);
            c0 = __fmaf_rn(fg, c0, ig * gt);
            const float hv = og * tanh_f(c0);
            if (wr0) hls[nxt][col][u0] = (_Float16)hv;
        }
        {
            const float ig = sigm(acc1[0]);
            const float fg = sigm(acc1[1]);
            const float gt = tanh_f(acc1[2]);
            const float og = sigm(acc1[3]);
            c1 = __fmaf_rn(fg, c1, ig * gt);
            const float hv = og * tanh_f(c1);
            if (wr1) hls[nxt][col][u1] = (_Float16)hv;
        }
        if (xw) hls[nxt][L][50] = xls[L][t + 1];  // t=511 reads pad: never consumed
        __syncthreads();
    }

    // ---- epilogue: out[b] = h_512 . W_fc + b_fc  (h_512 is in hls[0])
    if (w == 0) {
        float part = 0.0f;
        #pragma unroll
        for (int j = 0; j < 13; ++j) {
            const int u = 13 * g4 + j;
            if (u < H_DIM) part += (float)hls[0][col][u] * W_fc[u];
        }
        part += __shfl_xor(part, 16);
        part += __shfl_xor(part, 32);
        if (L < BPB) out[blockIdx.x * BPB + L] = part + b_fc[0];
    }
}

extern "C" void kernel_launch(void* const* d_in, const int* in_sizes, int n_in,
                              void* d_out, int out_size, void* d_ws, size_t ws_size,
                              hipStream_t stream) {
    const float* x    = (const float*)d_in[0];
    const float* W_ih = (const float*)d_in[1];
    const float* W_hh = (const float*)d_in[2];
    const float* b_ih = (const float*)d_in[3];
    const float* b_hh = (const float*)d_in[4];
    const float* W_fc = (const float*)d_in[5];
    const float* b_fc = (const float*)d_in[6];
    float* out = (float*)d_out;

    const int B = in_sizes[0] / T_LEN;   // 4096
    lstm_mfma<<<dim3(B / BPB), dim3(512), 0, stream>>>(
        x, W_ih, W_hh, b_ih, b_hh, W_fc, b_fc, out);
}